// Round 2
// baseline (1003.226 us; speedup 1.0000x reference)
//
#include <hip/hip_runtime.h>

// CubicalLayer: gather birth/death filtration values from a flattened 512^3
// volume via persistence-pair indices; zero pairs with death == birth.
//
// The direct random gather is DRAM row-activate limited (~0.8 TB/s effective:
// every 64B access is a row miss). Strategy: bin-then-gather.
//   K0: zero per-bin counters (in d_ws)
//   K1: partition 8M (idx,pos) entries into 2048 bins by idx>>16
//       (256 KiB of X per bin), exact per-block LDS-aggregated reservation
//   K2: one block per bin: gathers confined to a 256 KiB window of X
//       (dense, row-hit friendly, L2-resident reuse); scatter raw value
//       to out[pos] (32 MB output merges in L3 before writeback)
//   K3: streaming in-place pass applies the pair keep/zero logic
//
// Entry array (128 MiB) and output (32 MiB) both fit Infinity Cache (256 MiB),
// so their scatters merge to full lines before HBM writeback.
//
// NOTE: __builtin_nontemporal_* requires Clang ext_vector_type typedefs.

typedef int   v4i __attribute__((ext_vector_type(4)));
typedef int   v2i __attribute__((ext_vector_type(2)));
typedef float v4f __attribute__((ext_vector_type(4)));

#define NBINS     2048   // 2^27 elems >> 16 -> 2^11 bins, 256 KiB of X each
#define BIN_SHIFT 16
#define BIN_CAP   8192   // expected 4096/bin (uniform); 2x headroom (overflow
                         // prob for Poisson(4096) > 8192 is ~e^-1300)

// ---------------- K0: zero per-bin counters ----------------
__global__ void zero_counts_kernel(int* __restrict__ counts) {
    int t = blockIdx.x * blockDim.x + threadIdx.x;
    if (t < NBINS) counts[t] = 0;
}

// ---------------- K1: partition into bins ----------------
__global__ __launch_bounds__(256) void partition_kernel(
    const int* __restrict__ idx0, const int* __restrict__ idx1,
    int* __restrict__ counts, v2i* __restrict__ entries,
    int n4_0, int n4_total, int ch4)
{
    __shared__ int lhist[NBINS];
    const int t  = threadIdx.x;
    const int c0 = blockIdx.x * ch4;
    const int c1 = min(c0 + ch4, n4_total);

    for (int i = t; i < NBINS; i += 256) lhist[i] = 0;
    __syncthreads();

    // pass A: count this block's entries per bin (LDS-aggregated)
    for (int c = c0 + t; c < c1; c += 256) {
        const v4i* p = (c < n4_0)
            ? (reinterpret_cast<const v4i*>(idx0) + c)
            : (reinterpret_cast<const v4i*>(idx1) + (c - n4_0));
        v4i v = __builtin_nontemporal_load(p);
        atomicAdd(&lhist[(((unsigned)v.x) >> BIN_SHIFT) & (NBINS - 1)], 1);
        atomicAdd(&lhist[(((unsigned)v.y) >> BIN_SHIFT) & (NBINS - 1)], 1);
        atomicAdd(&lhist[(((unsigned)v.z) >> BIN_SHIFT) & (NBINS - 1)], 1);
        atomicAdd(&lhist[(((unsigned)v.w) >> BIN_SHIFT) & (NBINS - 1)], 1);
    }
    __syncthreads();

    // reserve a contiguous run per (block, bin); lhist[b] becomes the write cursor
    for (int b = t; b < NBINS; b += 256) {
        int c = lhist[b];
        lhist[b] = (c > 0) ? (b * BIN_CAP + atomicAdd(&counts[b], c)) : 0;
    }
    __syncthreads();

    // pass B: re-read (hits L3: 32 MB) and scatter (idx, pos) into reserved slots
    for (int c = c0 + t; c < c1; c += 256) {
        const v4i* p = (c < n4_0)
            ? (reinterpret_cast<const v4i*>(idx0) + c)
            : (reinterpret_cast<const v4i*>(idx1) + (c - n4_0));
        v4i v = __builtin_nontemporal_load(p);
        const int pos = c * 4;
        #pragma unroll
        for (int k = 0; k < 4; ++k) {
            int id = (k == 0) ? v.x : (k == 1) ? v.y : (k == 2) ? v.z : v.w;
            int b  = (((unsigned)id) >> BIN_SHIFT) & (NBINS - 1);
            int slot = atomicAdd(&lhist[b], 1);
            if (slot >= b * BIN_CAP && slot < (b + 1) * BIN_CAP) {
                v2i e; e.x = id; e.y = pos + k;
                entries[slot] = e;
            }
        }
    }
}

// ---------------- K2: per-bin gather + scatter raw values ----------------
__global__ __launch_bounds__(256) void gather_bins_kernel(
    const float* __restrict__ X, const int* __restrict__ counts,
    const v2i* __restrict__ entries, float* __restrict__ out)
{
    const int b = blockIdx.x;
    int cnt = counts[b];
    if (cnt > BIN_CAP) cnt = BIN_CAP;
    const v2i* e = entries + (size_t)b * BIN_CAP;
    for (int i = threadIdx.x; i < cnt; i += 256) {
        v2i p = e[i];
        out[p.y] = X[p.x];   // X load confined to this bin's 256 KiB window;
                             // out scatter merges in L3 (32 MB region)
    }
}

// ---------------- K3: in-place pair keep/zero ----------------
__global__ __launch_bounds__(256) void pair_filter_kernel(
    float* __restrict__ out, int n4)
{
    int i = blockIdx.x * 256 + threadIdx.x;
    if (i >= n4) return;
    v4f* p = reinterpret_cast<v4f*>(out) + i;
    v4f o = *p;
    bool k0 = o.y != o.x;   // |d-b| > 0  <=>  d != b (no NaNs)
    bool k1 = o.w != o.z;
    v4f r;
    r.x = k0 ? o.x : 0.0f;
    r.y = k0 ? o.y : 0.0f;
    r.z = k1 ? o.z : 0.0f;
    r.w = k1 ? o.w : 0.0f;
    *p = r;
}

// ---------------- fallback: direct-gather (previous passing kernel) ----------------
__global__ __launch_bounds__(256) void gather_diagram_kernel(
    const float* __restrict__ X,
    const int* __restrict__ idx0,
    const int* __restrict__ idx1,
    float* __restrict__ out,
    int n4_0, int n4_total)
{
    constexpr int C = 4;
    const int tid    = blockIdx.x * blockDim.x + threadIdx.x;
    const int stride = gridDim.x * blockDim.x;

    int  c[C];
    v4i  ij[C];
    bool ok[C];
    #pragma unroll
    for (int j = 0; j < C; ++j) {
        c[j]  = tid + j * stride;
        ok[j] = c[j] < n4_total;
        int cc = ok[j] ? c[j] : 0;
        const v4i* p = (cc < n4_0)
            ? reinterpret_cast<const v4i*>(idx0) + cc
            : reinterpret_cast<const v4i*>(idx1) + (cc - n4_0);
        ij[j] = __builtin_nontemporal_load(p);
    }

    float v[C][4];
    #pragma unroll
    for (int j = 0; j < C; ++j) {
        v[j][0] = X[ij[j].x];
        v[j][1] = X[ij[j].y];
        v[j][2] = X[ij[j].z];
        v[j][3] = X[ij[j].w];
    }

    #pragma unroll
    for (int j = 0; j < C; ++j) {
        bool k0 = v[j][1] != v[j][0];
        bool k1 = v[j][3] != v[j][2];
        v4f o;
        o.x = k0 ? v[j][0] : 0.0f;
        o.y = k0 ? v[j][1] : 0.0f;
        o.z = k1 ? v[j][2] : 0.0f;
        o.w = k1 ? v[j][3] : 0.0f;
        if (ok[j])
            __builtin_nontemporal_store(o, reinterpret_cast<v4f*>(out) + c[j]);
    }
}

extern "C" void kernel_launch(void* const* d_in, const int* in_sizes, int n_in,
                              void* d_out, int out_size, void* d_ws, size_t ws_size,
                              hipStream_t stream) {
    const float* X        = (const float*)d_in[0];
    const int*   indices0 = (const int*)d_in[1];
    const int*   indices1 = (const int*)d_in[2];
    float*       out      = (float*)d_out;

    const int n0       = in_sizes[1];           // int32 elements in idx0
    const int n1       = in_sizes[2];           // int32 elements in idx1
    const int n4_0     = n0 / 4;
    const int n4_total = (n0 + n1) / 4;

    // workspace layout: [counts: NBINS*4 B][pad to 64 KiB][entries: NBINS*BIN_CAP*8 B]
    const size_t entries_off = 65536;
    const size_t ws_need = entries_off + (size_t)NBINS * BIN_CAP * sizeof(int) * 2;

    if (ws_size < ws_need || (n0 & 3) || (n1 & 3) || n4_total <= 0 || d_ws == nullptr) {
        // fallback: direct gather (previous harness-verified kernel)
        constexpr int C = 4, BLOCK = 256;
        const int threads_needed = (n4_total + C - 1) / C;
        const int blocks = (threads_needed + BLOCK - 1) / BLOCK;
        if (blocks > 0)
            gather_diagram_kernel<<<blocks, BLOCK, 0, stream>>>(
                X, indices0, indices1, out, n4_0, n4_total);
        return;
    }

    int* counts  = (int*)d_ws;
    v2i* entries = (v2i*)((char*)d_ws + entries_off);

    zero_counts_kernel<<<(NBINS + 255) / 256, 256, 0, stream>>>(counts);

    constexpr int PART_BLOCKS = 256;
    const int ch4 = (n4_total + PART_BLOCKS - 1) / PART_BLOCKS;
    partition_kernel<<<PART_BLOCKS, 256, 0, stream>>>(
        indices0, indices1, counts, entries, n4_0, n4_total, ch4);

    gather_bins_kernel<<<NBINS, 256, 0, stream>>>(X, counts, entries, out);

    pair_filter_kernel<<<(n4_total + 255) / 256, 256, 0, stream>>>(out, n4_total);
}

// Round 3
// 932.501 us; speedup vs baseline: 1.0758x; 1.0758x over previous
//
#include <hip/hip_runtime.h>

// CubicalLayer: gather birth/death filtration values from a flattened 512^3
// volume (512 MB) via 8M persistence-pair indices; zero pairs with
// death == birth (min_pers = 0.0).
//
// Direct random gather is DRAM row-activate bound (~1.4 TB/s effective).
// Round-2's materialized bin-partition regressed (+253 us): the 8M scattered
// 8B entry-stores into a 128 MiB intermediate were themselves random traffic.
//
// This version: multi-pass chunked gather through Infinity Cache (L3).
// L3 (256 MiB) is a memory-side cache shared by all XCDs: a sequential
// stream of a 64 MB chunk of X fills it at full HBM row-hit bandwidth;
// gathers restricted to that chunk then hit L3 instead of DRAM row-misses.
//   for p in 0..8:  warm(chunk p)  ->  gather indices in [lo,hi)
//   then: streaming pair keep/zero pass over out.
// Working set per pass: chunk 64 MB + idx 32 MB + out 32 MB = 128 MB < L3.
// idx/out stay L3-resident across passes, so the 8x index re-scan is cheap.
// No workspace, no atomics, no intermediates.

typedef int   v4i __attribute__((ext_vector_type(4)));
typedef float v4f __attribute__((ext_vector_type(4)));

#define NCHUNK 8   // 512 MB / 8 = 64 MB chunks

// ---------------- warm: stream chunk into L2/L3 ----------------
__global__ __launch_bounds__(256) void warm_kernel(
    const v4f* __restrict__ Xc, int n16)
{
    int i = blockIdx.x * blockDim.x + threadIdx.x;
    float acc = 0.0f;
    if (i < n16) {
        v4f v = Xc[i];               // plain load: fills L2 + L3
        acc = v.x + v.y + v.z + v.w;
    }
    asm volatile("" :: "v"(acc));    // keep loads live without a store
}

// ---------------- per-pass range-restricted gather ----------------
__global__ __launch_bounds__(256) void gather_range_kernel(
    const float* __restrict__ X,
    const int* __restrict__ idx0,   // 2*P0 interleaved (birth, death)
    const int* __restrict__ idx1,   // 2*P1
    float* __restrict__ out,
    int n4_0, int n4_total, int lo, int hi)
{
    constexpr int C = 4;  // 16 index slots per thread
    const int tid    = blockIdx.x * blockDim.x + threadIdx.x;
    const int stride = gridDim.x * blockDim.x;

    int  c[C];
    v4i  ij[C];
    bool ok[C];
    #pragma unroll
    for (int j = 0; j < C; ++j) {
        c[j]  = tid + j * stride;
        ok[j] = c[j] < n4_total;
        int cc = ok[j] ? c[j] : 0;
        const v4i* p = (cc < n4_0)
            ? reinterpret_cast<const v4i*>(idx0) + cc
            : reinterpret_cast<const v4i*>(idx1) + (cc - n4_0);
        ij[j] = *p;                  // plain load: idx stays L3-resident
    }

    #pragma unroll
    for (int j = 0; j < C; ++j) {
        if (!ok[j]) continue;
        float* o = out + 4 * (size_t)c[j];
        #pragma unroll
        for (int k = 0; k < 4; ++k) {
            int id = (k == 0) ? ij[j].x : (k == 1) ? ij[j].y
                   : (k == 2) ? ij[j].z : ij[j].w;
            if (id >= lo && id < hi)
                o[k] = X[id];        // L3-hit gather (chunk just warmed)
        }
    }
}

// ---------------- final in-place pair keep/zero ----------------
__global__ __launch_bounds__(256) void pair_filter_kernel(
    float* __restrict__ out, int n4)
{
    int i = blockIdx.x * 256 + threadIdx.x;
    if (i >= n4) return;
    v4f* p = reinterpret_cast<v4f*>(out) + i;
    v4f o = *p;
    bool k0 = o.y != o.x;   // |d-b| > 0  <=>  d != b (no NaNs)
    bool k1 = o.w != o.z;
    v4f r;
    r.x = k0 ? o.x : 0.0f;
    r.y = k0 ? o.y : 0.0f;
    r.z = k1 ? o.z : 0.0f;
    r.w = k1 ? o.w : 0.0f;
    *p = r;
}

// ---------------- fallback: direct gather (harness-verified, 750 us) -------
__global__ __launch_bounds__(256) void gather_diagram_kernel(
    const float* __restrict__ X,
    const int* __restrict__ idx0,
    const int* __restrict__ idx1,
    float* __restrict__ out,
    int n4_0, int n4_total)
{
    constexpr int C = 4;
    const int tid    = blockIdx.x * blockDim.x + threadIdx.x;
    const int stride = gridDim.x * blockDim.x;

    int  c[C];
    v4i  ij[C];
    bool ok[C];
    #pragma unroll
    for (int j = 0; j < C; ++j) {
        c[j]  = tid + j * stride;
        ok[j] = c[j] < n4_total;
        int cc = ok[j] ? c[j] : 0;
        const v4i* p = (cc < n4_0)
            ? reinterpret_cast<const v4i*>(idx0) + cc
            : reinterpret_cast<const v4i*>(idx1) + (cc - n4_0);
        ij[j] = *p;
    }

    float v[C][4];
    #pragma unroll
    for (int j = 0; j < C; ++j) {
        v[j][0] = X[ij[j].x];
        v[j][1] = X[ij[j].y];
        v[j][2] = X[ij[j].z];
        v[j][3] = X[ij[j].w];
    }

    #pragma unroll
    for (int j = 0; j < C; ++j) {
        bool k0 = v[j][1] != v[j][0];
        bool k1 = v[j][3] != v[j][2];
        v4f o;
        o.x = k0 ? v[j][0] : 0.0f;
        o.y = k0 ? v[j][1] : 0.0f;
        o.z = k1 ? v[j][2] : 0.0f;
        o.w = k1 ? v[j][3] : 0.0f;
        if (ok[j]) {
            v4f* po = reinterpret_cast<v4f*>(out) + c[j];
            *po = o;
        }
    }
}

extern "C" void kernel_launch(void* const* d_in, const int* in_sizes, int n_in,
                              void* d_out, int out_size, void* d_ws, size_t ws_size,
                              hipStream_t stream) {
    const float* X        = (const float*)d_in[0];
    const int*   indices0 = (const int*)d_in[1];
    const int*   indices1 = (const int*)d_in[2];
    float*       out      = (float*)d_out;

    const int nX       = in_sizes[0];   // floats in X (512^3)
    const int n0       = in_sizes[1];   // int32 elements in idx0
    const int n1       = in_sizes[2];   // int32 elements in idx1
    const int n4_0     = n0 / 4;
    const int n4_total = (n0 + n1) / 4;

    if ((n0 & 3) || (n1 & 3) || n4_total <= 0 || nX <= 0) {
        // fallback: direct gather (previous harness-verified kernel)
        constexpr int C = 4, BLOCK = 256;
        const int threads_needed = (n4_total + C - 1) / C;
        const int blocks = (threads_needed + BLOCK - 1) / BLOCK;
        if (blocks > 0)
            gather_diagram_kernel<<<blocks, BLOCK, 0, stream>>>(
                X, indices0, indices1, out, n4_0, n4_total);
        return;
    }

    constexpr int C = 4, BLOCK = 256;
    const int threads_needed = (n4_total + C - 1) / C;
    const int gblocks = (threads_needed + BLOCK - 1) / BLOCK;   // 2048 @ 8M idx

    const int chunk = (nX + NCHUNK - 1) / NCHUNK;               // 16M floats
    for (int p = 0; p < NCHUNK; ++p) {
        const int lo = p * chunk;
        if (lo >= nX) break;
        const int hi = (lo + chunk < nX) ? (lo + chunk) : nX;
        const int n16 = (hi - lo) / 4;                          // v4f count
        if (n16 > 0)
            warm_kernel<<<(n16 + BLOCK - 1) / BLOCK, BLOCK, 0, stream>>>(
                reinterpret_cast<const v4f*>(X + lo), n16);
        gather_range_kernel<<<gblocks, BLOCK, 0, stream>>>(
            X, indices0, indices1, out, n4_0, n4_total, lo, hi);
    }

    pair_filter_kernel<<<(n4_total + 255) / 256, 256, 0, stream>>>(out, n4_total);
}